// Round 14
// baseline (1322.174 us; speedup 1.0000x reference)
//
#include <hip/hip_runtime.h>
#include <hip/hip_bf16.h>
#include <math.h>

#define B_N 8192
#define T_N 4
#define D_N 1024
#define BM  128
#define BN  256
#define NT  16                 // 1024/64 K-tiles (64 fp8 bytes per tile-row)
#define NBLK 1056              // sum_{bx=0}^{31} (2bx+2) = 1056 = 8*132

typedef float f32x16 __attribute__((ext_vector_type(16)));
typedef int i32x4 __attribute__((ext_vector_type(4)));
typedef int i32x8 __attribute__((ext_vector_type(8)));

// ---- order-preserving float <-> uint map ----
__device__ inline unsigned int f2u_ord(float f) {
    unsigned int b = __float_as_uint(f);
    return (b & 0x80000000u) ? ~b : (b | 0x80000000u);
}
__device__ inline float u2f_ord(unsigned int u) {
    unsigned int b = (u & 0x80000000u) ? (u & 0x7FFFFFFFu) : ~u;
    return __uint_as_float(b);
}

// f32 -> OCP e4m3fn, RNE. Valid for finite |x| < 2 (ours: |x| <= ~1).
__device__ inline unsigned int f2e4m3(float f) {
    unsigned int u = __float_as_uint(f);
    unsigned int sgn = (u >> 24) & 0x80u;
    int e = (int)((u >> 23) & 0xFFu) - 127;
    unsigned int m = u & 0x7FFFFFu;
    if (e >= -6) {  // normal fp8 range (bias 7)
        unsigned int mant = m >> 20;
        unsigned int rest = m & 0xFFFFFu;
        mant += (rest > 0x80000u) || (rest == 0x80000u && (mant & 1u));
        unsigned int exp8 = (unsigned)(e + 7);
        if (mant == 8u) { mant = 0u; exp8 += 1u; }
        return sgn | (exp8 << 3) | mant;
    } else {        // subnormal: quantum 2^-9
        float a = fabsf(f) * 512.0f;
        int q = (int)rintf(a);
        if (q >= 8) return sgn | 0x08u;
        return sgn | (unsigned)q;
    }
}

// in: [B][T][D] f32 ; out xn: [T][B][D] fp8 e4m3 (normalized rows), LINEAR layout.
// Also zeroes rowmax (fused init: first 128 blocks).
__global__ __launch_bounds__(256) void norm_kernel(const float* __restrict__ in,
                                                   unsigned char* __restrict__ xn,
                                                   unsigned int* __restrict__ rowmax) {
    if (blockIdx.x < (T_N * B_N) / 256) rowmax[blockIdx.x * 256 + threadIdx.x] = 0u;

    const int row  = blockIdx.x * 4 + (threadIdx.x >> 6);
    const int lane = threadIdx.x & 63;
    const int b = row >> 2;
    const int t = row & 3;
    const float* src = in + (size_t)row * D_N;

    float4 v[4];
    float ss = 0.f;
#pragma unroll
    for (int i = 0; i < 4; ++i) {
        v[i] = reinterpret_cast<const float4*>(src)[lane + 64 * i];
        ss += v[i].x * v[i].x + v[i].y * v[i].y + v[i].z * v[i].z + v[i].w * v[i].w;
    }
#pragma unroll
    for (int off = 32; off; off >>= 1) ss += __shfl_xor(ss, off, 64);
    const float rn = 1.0f / fmaxf(sqrtf(ss), 1e-12f);

    unsigned int* dst = reinterpret_cast<unsigned int*>(xn + ((size_t)t * B_N + b) * D_N);
#pragma unroll
    for (int i = 0; i < 4; ++i) {
        unsigned int p = f2e4m3(v[i].x * rn) | (f2e4m3(v[i].y * rn) << 8) |
                         (f2e4m3(v[i].z * rn) << 16) | (f2e4m3(v[i].w * rn) << 24);
        dst[lane + 64 * i] = p;
    }
}

#define GLOAD_LDS16(g, l)                                                              \
    __builtin_amdgcn_global_load_lds(                                                  \
        (const __attribute__((address_space(1))) unsigned int*)(g),                    \
        (__attribute__((address_space(3))) unsigned int*)(l), 16, 0, 0)

// Gram upper-triangle, MX-fp8 (unit scales), tile 128x256, BK=64B, 8 waves
// (2M x 4N, 64x64 C per wave via 2x2 of 32x32), TWO blocks/CU (72KB LDS,
// launch_bounds(512,4)). R13-proven control flow: triple-buffered LDS,
// horizon-2 staging, 1 barrier + 1 counted vmcnt(3) per K-tile.
// MFMA: mfma_scale_f32_32x32x64_f8f6f4 with E8M0 scale 0x7F (=1.0) -> plain
// fp8 semantics at 2.3x the 16x16x32 pipe rate. Lane operand: row=lane&31,
// 32B K-chunk h=lane>>5 -> two ds_read_b128 at swizzled pos 2h^s, (2h^s)^1.
// LDS swizzle: unit' = U ^ ((row>>2)&3) (proven 2-way-max pattern).
__global__ __launch_bounds__(512, 4) void gemm_rowmax_kernel(const unsigned char* __restrict__ xn,
                                                             unsigned int* __restrict__ rowmax) {
    const int t = blockIdx.z;
    // XCD-chunked bijective swizzle (1056 = 8*132)
    const int bid = blockIdx.x;
    int l = (bid & 7) * (NBLK / 8) + (bid >> 3);
    int bx = 0;
    while (l >= 2 * bx + 2) { l -= 2 * bx + 2; ++bx; }
    const int by = l;   // 0 .. 2bx+1  (128-row block; 256-col block bx)

    const unsigned char* X = xn + (size_t)t * B_N * D_N;

    __shared__ __align__(16) unsigned char lds[73728];  // 3 bufs x (A 8K + B 16K)

    const int tid  = threadIdx.x;
    const int lane = tid & 63;
    const int wv   = tid >> 6;   // 0..7
    const int wm   = wv >> 2;    // M half (64 rows)
    const int wn   = wv & 3;     // N quarter (64 cols)

    // staging source (per lane): dest slot row = wv*16 + (lane>>2), pos = lane&3;
    // LDS pos p holds unit u = p ^ ((row>>2)&3) -> source pos = (lane&3)^((lane>>4)&3)
    const int srow = lane >> 2;
    const int spos = (lane & 3) ^ ((lane >> 4) & 3);
    const unsigned char* gA  = X + (size_t)(by * BM + wv * 16 + srow) * D_N + spos * 16;
    const unsigned char* gB0 = X + (size_t)(bx * BN + wv * 16 + srow) * D_N + spos * 16;
    const unsigned char* gB1 = gB0 + (size_t)128 * D_N;

    // fragment read: row = lane&31, K-chunk h = lane>>5 (32B = units {2h,2h+1});
    // swizzled pos0 = (2h) ^ ((lane>>2)&3); second unit at pos0^1.
    const int h  = lane >> 5;
    const int lc = lane & 31;
    const unsigned pos0 = (unsigned)((2 * h) ^ ((lane >> 2) & 3));
    const unsigned off0 = (unsigned)lc * 64u + pos0 * 16u;
    const unsigned off1 = (unsigned)lc * 64u + (pos0 ^ 1u) * 16u;
    const unsigned aBase = (unsigned)wm * 4096u;
    const unsigned bBase = 8192u + (unsigned)wn * 4096u;

    f32x16 acc[2][2];
#pragma unroll
    for (int m = 0; m < 2; ++m)
#pragma unroll
        for (int n = 0; n < 2; ++n)
#pragma unroll
            for (int k = 0; k < 16; ++k) acc[m][n][k] = 0.f;

#define BARRIER asm volatile("s_barrier" ::: "memory")
#define VMCNT(N) asm volatile("s_waitcnt vmcnt(" #N ")" ::: "memory")
#define STAGE(buf, kc)                                                                  \
    GLOAD_LDS16(gA + (kc),  &lds[(buf) + wv * 1024u]);                                  \
    GLOAD_LDS16(gB0 + (kc), &lds[(buf) + 8192u + wv * 1024u]);                          \
    GLOAD_LDS16(gB1 + (kc), &lds[(buf) + 16384u + wv * 1024u]);

    // prologue: stage tile 0 -> buf0, tile 1 -> buf1; gate tile 0
    STAGE(0u, 0)
    STAGE(24576u, 64)
    VMCNT(3);  // tile 0 staged (per-wave); barrier in body(0) makes it collective

    int cur = 0;  // kt % 3
    for (int kt = 0; kt < NT; ++kt) {
        BARRIER;  // all waves: tile kt staged, prior-tile reads done

        if (kt + 2 < NT) {
            int n2 = cur - 1; if (n2 < 0) n2 += 3;   // (cur+2)%3
            STAGE((unsigned)n2 * 24576u, (kt + 2) * 64)
        }

        const unsigned bb = (unsigned)cur * 24576u;

        i32x8 bV[2];
#pragma unroll
        for (int nf = 0; nf < 2; ++nf) {
            const unsigned rB = bb + bBase + (unsigned)nf * 2048u;
            i32x4 lo = *reinterpret_cast<const i32x4*>(&lds[rB + off0]);
            i32x4 hi = *reinterpret_cast<const i32x4*>(&lds[rB + off1]);
            bV[nf] = __builtin_shufflevector(lo, hi, 0, 1, 2, 3, 4, 5, 6, 7);
        }
        __builtin_amdgcn_s_setprio(1);
#pragma unroll
        for (int mf = 0; mf < 2; ++mf) {
            const unsigned rA = bb + aBase + (unsigned)mf * 2048u;
            i32x4 lo = *reinterpret_cast<const i32x4*>(&lds[rA + off0]);
            i32x4 hi = *reinterpret_cast<const i32x4*>(&lds[rA + off1]);
            i32x8 aV = __builtin_shufflevector(lo, hi, 0, 1, 2, 3, 4, 5, 6, 7);
            acc[mf][0] = __builtin_amdgcn_mfma_scale_f32_32x32x64_f8f6f4(
                aV, bV[0], acc[mf][0], 0, 0, 0, 0x7F7F7F7F, 0, 0x7F7F7F7F);
            acc[mf][1] = __builtin_amdgcn_mfma_scale_f32_32x32x64_f8f6f4(
                aV, bV[1], acc[mf][1], 0, 0, 0, 0x7F7F7F7F, 0, 0x7F7F7F7F);
        }
        __builtin_amdgcn_s_setprio(0);

        // gate: retire tile kt+1's stages (issued last body), keep kt+2's in flight
        if (kt < NT - 2) { VMCNT(3); } else { VMCNT(0); }

        cur = (cur == 2) ? 0 : cur + 1;
    }

    // epilogue: 32x32 C/D layout: col = lane&31, row = (reg&3) + 8*(reg>>2) + 4*(lane>>5)
    const int rbase = by * BM + wm * 64;
    const int cbase = bx * BN + wn * 64;
    unsigned int* rm = rowmax + t * B_N;

    // row-max over this wave's 64 cols (diag excluded); each 32-lane half holds one row
#pragma unroll
    for (int mi = 0; mi < 2; ++mi) {
#pragma unroll
        for (int r = 0; r < 16; ++r) {
            const int row = rbase + mi * 32 + (r & 3) + 8 * (r >> 2) + 4 * h;
            float mx = -2.0f;
#pragma unroll
            for (int ni = 0; ni < 2; ++ni) {
                const int col = cbase + ni * 32 + lc;
                float v = acc[mi][ni][r];
                if (col != row) mx = fmaxf(mx, v);
            }
#pragma unroll
            for (int off = 1; off < 32; off <<= 1) mx = fmaxf(mx, __shfl_xor(mx, off, 64));
            if (lc == 0) atomicMax(&rm[row], f2u_ord(mx));
        }
    }
    // col-max over this wave's 64 rows (covers mirrored lower-triangle part)
#pragma unroll
    for (int ni = 0; ni < 2; ++ni) {
        const int col = cbase + ni * 32 + lc;
        float mx = -2.0f;
#pragma unroll
        for (int mi = 0; mi < 2; ++mi)
#pragma unroll
            for (int r = 0; r < 16; ++r) {
                const int row = rbase + mi * 32 + (r & 3) + 8 * (r >> 2) + 4 * h;
                float v = acc[mi][ni][r];
                if (col != row) mx = fmaxf(mx, v);
            }
        mx = fmaxf(mx, __shfl_xor(mx, 32, 64));
        if (lane < 32) atomicMax(&rm[col], f2u_ord(mx));
    }
#undef BARRIER
#undef VMCNT
#undef STAGE
}

__global__ __launch_bounds__(256) void finish_partial_kernel(const unsigned int* __restrict__ rowmax,
                                                             float* __restrict__ partials) {
    __shared__ float sbuf[4];
    float s = 0.f;
    for (int i = blockIdx.x * 256 + threadIdx.x; i < T_N * B_N; i += 64 * 256) {
        float m  = u2f_ord(rowmax[i]);
        float d2 = fmaxf(2.0f - 2.0f * m, 0.0f);
        s += logf(sqrtf(d2) + 1e-12f);
    }
#pragma unroll
    for (int off = 32; off; off >>= 1) s += __shfl_xor(s, off, 64);
    const int w = threadIdx.x >> 6;
    if ((threadIdx.x & 63) == 0) sbuf[w] = s;
    __syncthreads();
    if (threadIdx.x == 0) partials[blockIdx.x] = sbuf[0] + sbuf[1] + sbuf[2] + sbuf[3];
}

__global__ __launch_bounds__(64) void finish_final_kernel(const float* __restrict__ partials,
                                                          float* __restrict__ out) {
    float s = partials[threadIdx.x];
#pragma unroll
    for (int off = 32; off; off >>= 1) s += __shfl_xor(s, off, 64);
    if (threadIdx.x == 0) out[0] = -s / (float)(T_N * B_N);
}

extern "C" void kernel_launch(void* const* d_in, const int* in_sizes, int n_in,
                              void* d_out, int out_size, void* d_ws, size_t ws_size,
                              hipStream_t stream) {
    const float* in = (const float*)d_in[0];
    unsigned char* xn = (unsigned char*)d_ws;  // 32 MB fp8 [T][B][D], linear
    unsigned int* rowmax = (unsigned int*)((char*)d_ws + (size_t)T_N * B_N * D_N);
    float* partials = (float*)((char*)d_ws + (size_t)T_N * B_N * D_N + (size_t)T_N * B_N * 4);
    float* out = (float*)d_out;

    norm_kernel<<<(B_N * T_N) / 4, 256, 0, stream>>>(in, xn, rowmax);
    dim3 g(NBLK, 1, T_N);
    gemm_rowmax_kernel<<<g, 512, 0, stream>>>(xn, rowmax);
    finish_partial_kernel<<<64, 256, 0, stream>>>(rowmax, partials);
    finish_final_kernel<<<1, 64, 0, stream>>>(partials, out);
}

// Round 15
// 218.616 us; speedup vs baseline: 6.0479x; 6.0479x over previous
//
#include <hip/hip_runtime.h>
#include <hip/hip_bf16.h>
#include <math.h>

#define B_N 8192
#define T_N 4
#define D_N 1024
#define BM  128
#define BN  256
#define NT  16                 // 1024/64 K-tiles (64 fp8 bytes per tile-row)
#define NBLK 1056              // sum_{bx=0}^{31} (2bx+2) = 1056 = 8*132

typedef float f32x4 __attribute__((ext_vector_type(4)));
typedef long longx2 __attribute__((ext_vector_type(2)));

// ---- order-preserving float <-> uint map ----
__device__ inline unsigned int f2u_ord(float f) {
    unsigned int b = __float_as_uint(f);
    return (b & 0x80000000u) ? ~b : (b | 0x80000000u);
}
__device__ inline float u2f_ord(unsigned int u) {
    unsigned int b = (u & 0x80000000u) ? (u & 0x7FFFFFFFu) : ~u;
    return __uint_as_float(b);
}

// f32 -> OCP e4m3fn, RNE. Valid for finite |x| < 2 (ours: |x| <= ~1).
__device__ inline unsigned int f2e4m3(float f) {
    unsigned int u = __float_as_uint(f);
    unsigned int sgn = (u >> 24) & 0x80u;
    int e = (int)((u >> 23) & 0xFFu) - 127;
    unsigned int m = u & 0x7FFFFFu;
    if (e >= -6) {  // normal fp8 range (bias 7)
        unsigned int mant = m >> 20;
        unsigned int rest = m & 0xFFFFFu;
        mant += (rest > 0x80000u) || (rest == 0x80000u && (mant & 1u));
        unsigned int exp8 = (unsigned)(e + 7);
        if (mant == 8u) { mant = 0u; exp8 += 1u; }
        return sgn | (exp8 << 3) | mant;
    } else {        // subnormal: quantum 2^-9
        float a = fabsf(f) * 512.0f;
        int q = (int)rintf(a);
        if (q >= 8) return sgn | 0x08u;
        return sgn | (unsigned)q;
    }
}

// in: [B][T][D] f32 ; out xn: [T][B][D] fp8 e4m3 (normalized rows), UNIT-PAIRED:
// within each 64B K-block, 8B piece q (q=0..7) stored at ((q&3)<<1)|(q>>2) ->
// 16B unit U holds pieces {U, U+4} = (k-half0, k-half1) for MFMA lane kq=U.
// Also zeroes rowmax (fused init: first 128 blocks).
__global__ __launch_bounds__(256) void norm_kernel(const float* __restrict__ in,
                                                   unsigned char* __restrict__ xn,
                                                   unsigned int* __restrict__ rowmax) {
    if (blockIdx.x < (T_N * B_N) / 256) rowmax[blockIdx.x * 256 + threadIdx.x] = 0u;

    const int row  = blockIdx.x * 4 + (threadIdx.x >> 6);
    const int lane = threadIdx.x & 63;
    const int b = row >> 2;
    const int t = row & 3;
    const float* src = in + (size_t)row * D_N;

    float4 v[4];
    float ss = 0.f;
#pragma unroll
    for (int i = 0; i < 4; ++i) {
        v[i] = reinterpret_cast<const float4*>(src)[lane + 64 * i];
        ss += v[i].x * v[i].x + v[i].y * v[i].y + v[i].z * v[i].z + v[i].w * v[i].w;
    }
#pragma unroll
    for (int off = 32; off; off >>= 1) ss += __shfl_xor(ss, off, 64);
    const float rn = 1.0f / fmaxf(sqrtf(ss), 1e-12f);

    unsigned int* dst = reinterpret_cast<unsigned int*>(xn + ((size_t)t * B_N + b) * D_N);
#pragma unroll
    for (int i = 0; i < 4; ++i) {
        unsigned int p = f2e4m3(v[i].x * rn) | (f2e4m3(v[i].y * rn) << 8) |
                         (f2e4m3(v[i].z * rn) << 16) | (f2e4m3(v[i].w * rn) << 24);
        const int w  = lane + 64 * i;
        const int pp = (((w >> 1) & 3) << 1) | ((w >> 3) & 1);   // permuted piece pos
        const int dw = (w & ~15) | (pp << 1) | (w & 1);
        dst[dw] = p;
    }
}

#define GLOAD_LDS16(g, l)                                                              \
    __builtin_amdgcn_global_load_lds(                                                  \
        (const __attribute__((address_space(1))) unsigned int*)(g),                    \
        (__attribute__((address_space(3))) unsigned int*)(l), 16, 0, 0)

// Gram upper-triangle, fp8 e4m3 (unit-paired), tile 128x256, BK=64B, 8 waves
// (2M x 4N, 64x64 C per wave), TWO blocks co-resident per CU (72KB LDS,
// launch_bounds(512,4)): independent barrier groups fill each other's stall
// windows (m114). R11/R13-proven config: triple-buffered LDS, horizon-2
// staging, 1 barrier + 1 counted vmcnt(3) per K-tile.
// LDS swizzle: unit' = U ^ ((row>>2)&3) (proven b128 pattern, 2-way max).
__global__ __launch_bounds__(512, 4) void gemm_rowmax_kernel(const unsigned char* __restrict__ xn,
                                                             unsigned int* __restrict__ rowmax) {
    const int t = blockIdx.z;
    // XCD-chunked bijective swizzle (1056 = 8*132); each XCD gets a contiguous
    // bx range -> B-panel stays in its L2.
    const int bid = blockIdx.x;
    int l = (bid & 7) * (NBLK / 8) + (bid >> 3);
    int bx = 0;
    while (l >= 2 * bx + 2) { l -= 2 * bx + 2; ++bx; }
    const int by = l;   // 0 .. 2bx+1  (128-row block; 256-col block bx)

    const unsigned char* X = xn + (size_t)t * B_N * D_N;

    __shared__ __align__(16) unsigned char lds[73728];  // 3 bufs x (A 8K + B 16K)

    const int tid  = threadIdx.x;
    const int lane = tid & 63;
    const int wv   = tid >> 6;   // 0..7
    const int wm   = wv >> 2;    // M half (64 rows)
    const int wn   = wv & 3;     // N quarter (64 cols)

    // staging source (per lane): dest slot row = wv*16 + (lane>>2), pos = lane&3;
    // LDS pos p holds unit u = p ^ ((row>>2)&3) -> source pos = (lane&3)^((lane>>4)&3)
    const int srow = lane >> 2;
    const int spos = (lane & 3) ^ ((lane >> 4) & 3);
    const unsigned char* gA  = X + (size_t)(by * BM + wv * 16 + srow) * D_N + spos * 16;
    const unsigned char* gB0 = X + (size_t)(bx * BN + wv * 16 + srow) * D_N + spos * 16;
    const unsigned char* gB1 = gB0 + (size_t)128 * D_N;

    // fragment read: row r0 = lane&15, unit kq = lane>>4, pos = kq ^ ((r0>>2)&3)
    const unsigned rdoff = (unsigned)(lane & 15) * 64u +
                           (unsigned)(((lane >> 4) ^ (lane >> 2)) & 3) * 16u;

    f32x4 acc[4][4];
#pragma unroll
    for (int m = 0; m < 4; ++m)
#pragma unroll
        for (int n = 0; n < 4; ++n) acc[m][n] = (f32x4){0.f, 0.f, 0.f, 0.f};

#define BARRIER asm volatile("s_barrier" ::: "memory")
#define VMCNT(N) asm volatile("s_waitcnt vmcnt(" #N ")" ::: "memory")
#define STAGE(buf, kc)                                                                  \
    GLOAD_LDS16(gA + (kc),  &lds[(buf) + wv * 1024u]);                                  \
    GLOAD_LDS16(gB0 + (kc), &lds[(buf) + 8192u + wv * 1024u]);                          \
    GLOAD_LDS16(gB1 + (kc), &lds[(buf) + 16384u + wv * 1024u]);

    // prologue: stage tile 0 -> buf0, tile 1 -> buf1; gate tile 0
    STAGE(0u, 0)
    STAGE(24576u, 64)
    VMCNT(3);  // tile 0 staged (per-wave); barrier in body(0) makes it collective

    int cur = 0;  // kt % 3
    for (int kt = 0; kt < NT; ++kt) {
        BARRIER;  // all waves: tile kt staged, prior-tile reads done

        if (kt + 2 < NT) {
            int n2 = cur - 1; if (n2 < 0) n2 += 3;   // (cur+2)%3
            STAGE((unsigned)n2 * 24576u, (kt + 2) * 64)
        }

        const unsigned bb = (unsigned)cur * 24576u;

        longx2 bV[4];
#pragma unroll
        for (int nf = 0; nf < 4; ++nf) {
            const unsigned rB = bb + 8192u + (unsigned)wn * 4096u + (unsigned)nf * 1024u + rdoff;
            bV[nf] = *reinterpret_cast<const longx2*>(&lds[rB]);
        }
        __builtin_amdgcn_s_setprio(1);
#pragma unroll
        for (int mf = 0; mf < 4; ++mf) {
            const unsigned rA = bb + (unsigned)wm * 4096u + (unsigned)mf * 1024u + rdoff;
            longx2 aV = *reinterpret_cast<const longx2*>(&lds[rA]);
#pragma unroll
            for (int nf = 0; nf < 4; ++nf) {
                acc[mf][nf] = __builtin_amdgcn_mfma_f32_16x16x32_fp8_fp8(
                    aV[0], bV[nf][0], acc[mf][nf], 0, 0, 0);
                acc[mf][nf] = __builtin_amdgcn_mfma_f32_16x16x32_fp8_fp8(
                    aV[1], bV[nf][1], acc[mf][nf], 0, 0, 0);
            }
        }
        __builtin_amdgcn_s_setprio(0);

        // gate: retire tile kt+1's stages (issued last body), keep kt+2's in flight
        if (kt < NT - 2) { VMCNT(3); } else { VMCNT(0); }

        cur = (cur == 2) ? 0 : cur + 1;
    }

    // epilogue: C/D layout col = lane&15, row = (lane>>4)*4 + reg
    const int rbase = by * BM + wm * 64;
    const int cbase = bx * BN + wn * 64;
    unsigned int* rm = rowmax + t * B_N;

    // row-max over this wave's 64 cols (diag excluded)
#pragma unroll
    for (int m = 0; m < 4; ++m) {
#pragma unroll
        for (int r = 0; r < 4; ++r) {
            const int row = rbase + m * 16 + (lane >> 4) * 4 + r;
            float mx = -2.0f;
#pragma unroll
            for (int n = 0; n < 4; ++n) {
                const int col = cbase + n * 16 + (lane & 15);
                float v = acc[m][n][r];
                if (col != row) mx = fmaxf(mx, v);
            }
#pragma unroll
            for (int off = 1; off < 16; off <<= 1) mx = fmaxf(mx, __shfl_xor(mx, off, 64));
            if ((lane & 15) == 0) atomicMax(&rm[row], f2u_ord(mx));
        }
    }
    // col-max over this wave's 64 rows (covers mirrored lower-triangle part)
#pragma unroll
    for (int n = 0; n < 4; ++n) {
        const int col = cbase + n * 16 + (lane & 15);
        float mx = -2.0f;
#pragma unroll
        for (int m = 0; m < 4; ++m)
#pragma unroll
            for (int r = 0; r < 4; ++r) {
                const int row = rbase + m * 16 + (lane >> 4) * 4 + r;
                float v = acc[m][n][r];
                if (col != row) mx = fmaxf(mx, v);
            }
        mx = fmaxf(mx, __shfl_xor(mx, 16, 64));
        mx = fmaxf(mx, __shfl_xor(mx, 32, 64));
        if ((lane >> 4) == 0) atomicMax(&rm[col], f2u_ord(mx));
    }
#undef BARRIER
#undef VMCNT
#undef STAGE
}

__global__ __launch_bounds__(256) void finish_partial_kernel(const unsigned int* __restrict__ rowmax,
                                                             float* __restrict__ partials) {
    __shared__ float sbuf[4];
    float s = 0.f;
    for (int i = blockIdx.x * 256 + threadIdx.x; i < T_N * B_N; i += 64 * 256) {
        float m  = u2f_ord(rowmax[i]);
        float d2 = fmaxf(2.0f - 2.0f * m, 0.0f);
        s += logf(sqrtf(d2) + 1e-12f);
    }
#pragma unroll
    for (int off = 32; off; off >>= 1) s += __shfl_xor(s, off, 64);
    const int w = threadIdx.x >> 6;
    if ((threadIdx.x & 63) == 0) sbuf[w] = s;
    __syncthreads();
    if (threadIdx.x == 0) partials[blockIdx.x] = sbuf[0] + sbuf[1] + sbuf[2] + sbuf[3];
}

__global__ __launch_bounds__(64) void finish_final_kernel(const float* __restrict__ partials,
                                                          float* __restrict__ out) {
    float s = partials[threadIdx.x];
#pragma unroll
    for (int off = 32; off; off >>= 1) s += __shfl_xor(s, off, 64);
    if (threadIdx.x == 0) out[0] = -s / (float)(T_N * B_N);
}

extern "C" void kernel_launch(void* const* d_in, const int* in_sizes, int n_in,
                              void* d_out, int out_size, void* d_ws, size_t ws_size,
                              hipStream_t stream) {
    const float* in = (const float*)d_in[0];
    unsigned char* xn = (unsigned char*)d_ws;  // 32 MB fp8 [T][B][D], unit-paired
    unsigned int* rowmax = (unsigned int*)((char*)d_ws + (size_t)T_N * B_N * D_N);
    float* partials = (float*)((char*)d_ws + (size_t)T_N * B_N * D_N + (size_t)T_N * B_N * 4);
    float* out = (float*)d_out;

    norm_kernel<<<(B_N * T_N) / 4, 256, 0, stream>>>(in, xn, rowmax);
    dim3 g(NBLK, 1, T_N);
    gemm_rowmax_kernel<<<g, 512, 0, stream>>>(xn, rowmax);
    finish_partial_kernel<<<64, 256, 0, stream>>>(rowmax, partials);
    finish_final_kernel<<<1, 64, 0, stream>>>(partials, out);
}